// Round 8
// baseline (138.666 us; speedup 1.0000x reference)
//
#include <hip/hip_runtime.h>
#include <hip/hip_bf16.h>

typedef __bf16    bf16x8  __attribute__((ext_vector_type(8)));
typedef __bf16    bf16x4  __attribute__((ext_vector_type(4)));
typedef _Float16  half8   __attribute__((ext_vector_type(8)));
typedef _Float16  half4   __attribute__((ext_vector_type(4)));
typedef _Float16  half2   __attribute__((ext_vector_type(2)));
typedef float     floatx4 __attribute__((ext_vector_type(4)));

constexpr int Bc  = 2;
constexpr int Hc  = 16;
constexpr int Lc  = 2048;
constexpr int Dc  = 64;
constexpr int BHn = Bc * Hc;     // 32
constexpr int BM  = 128;         // query rows per q-tile
constexpr int BN  = 128;         // keys per kv tile
constexpr int NQT = Lc / BM;     // 16 query tiles
constexpr int LDK = 72;          // K padded stride (bf16 elems) -> row = 144 B
constexpr int LDV = 136;         // V^T padded stride (f16 elems) -> row = 272 B
constexpr int LDQ = 72;          // Q staging stride (bf16) in buf1's K area
constexpr int KBYTES = BN * LDK * 2;            // 18432
constexpr int VBYTES = Dc * LDV * 2;            // 17408
constexpr int TILE_BYTES = KBYTES + VBYTES;     // 35840 (= LDS image of one tile)

static __device__ __forceinline__ half2 pack_f16(float a, float b) {
    return __builtin_bit_cast(half2, __builtin_amdgcn_cvt_pkrtz(a, b));
}

static __device__ __forceinline__ void dma16(const void* g, void* l) {
    __builtin_amdgcn_global_load_lds(
        (const __attribute__((address_space(1))) void*)g,
        (__attribute__((address_space(3))) void*)l, 16, 0, 0);
}

// ---- pre-pass: write K/V tiles in the exact padded LDS image ----
// kv layout: [bh][tile=16][ K: 128 rows x 144 B | V^T: 64 rows x 272 B ] = 35840 B/tile
// V^T value at [d][pcol] = V[key(pcol)][d]; pcol permutation within each 32-key group:
// k5 -> 8*((k5>>2)&3) + 4*(k5>>4) + (k5&3)  (makes PV A-frags b128-contiguous)
__global__ void prep(const float* __restrict__ kp, const float* __restrict__ vp,
                     char* __restrict__ kv) {
    const int bid = blockIdx.x, tid = threadIdx.x;
    if (bid < 1024) {
        // K part: 1024 blocks x 256 threads; 4 threads per K row (16 d each)
        const int R    = bid * 64 + (tid >> 2);   // global row: bh*2048 + key
        const int s    = tid & 3;
        const int bh   = R >> 11;
        const int key  = R & 2047;
        const int tile = key >> 7;
        const int krow = key & 127;
        const float* src = kp + (size_t)R * 64 + s * 16;
        char* dst = kv + (size_t)(bh * 16 + tile) * TILE_BYTES + krow * 144 + s * 32;
        #pragma unroll
        for (int h = 0; h < 2; ++h) {
            floatx4 a = *(const floatx4*)(src + h * 8);
            floatx4 b = *(const floatx4*)(src + h * 8 + 4);
            bf16x8 o;
            o[0] = (__bf16)a[0]; o[1] = (__bf16)a[1]; o[2] = (__bf16)a[2]; o[3] = (__bf16)a[3];
            o[4] = (__bf16)b[0]; o[5] = (__bf16)b[1]; o[6] = (__bf16)b[2]; o[7] = (__bf16)b[3];
            *(bf16x8*)(dst + h * 16) = o;
        }
    } else {
        // V part: 1024 blocks; block handles 64 keys (half a tile) x 64 d
        const int vb   = bid - 1024;
        const int bh   = vb >> 5, kt = vb & 31;
        const int key  = kt * 64 + (tid & 63);
        const int tile = kt >> 1;
        const int kwt  = (kt & 1) * 64 + (tid & 63);   // key within tile
        const int k5   = kwt & 31;
        const int pcol = (kwt & ~31) | (((k5 >> 2) & 3) * 8 + ((k5 >> 4) & 1) * 4 + (k5 & 3));
        const int d0   = (tid >> 6) * 16;
        const float* src = vp + ((size_t)bh * Lc + key) * Dc;
        _Float16* dst = (_Float16*)(kv + (size_t)(bh * 16 + tile) * TILE_BYTES + KBYTES);
        #pragma unroll
        for (int i = 0; i < 16; ++i) {
            const int d = d0 + i;
            dst[(size_t)d * LDV + pcol] = (_Float16)src[d];
        }
    }
}

// ---- main kernel: 512 blocks (2/CU), serial complement pair inside each block ----
// Block (bh, s) processes q-tile s then q-tile 15-s sequentially: every block runs
// exactly 17 iterations -> all blocks isochronous, every CU keeps 8 waves active
// for the whole kernel (R2's spatial pairing left CUs running a lone 4-wave block).
__global__ __launch_bounds__(256, 2)
void taylor_attn(const float* __restrict__ qp, const char* __restrict__ kv,
                 float* __restrict__ op)
{
    __shared__ __align__(16) char smem[2 * TILE_BYTES];   // 71680 B: buf0 | buf1

    const int tid  = threadIdx.x;
    const int wv   = tid >> 6;
    const int lane = tid & 63;
    const int lm   = lane & 15;
    const int quad = lane >> 4;
    const int wq   = wv >> 1;   // q-half owner: rows [64*wq, 64*wq+64)
    const int wk   = wv & 1;    // key-half owner: keys [64*wk, 64*wk+64)

    const int bh = (int)(blockIdx.x & 31);
    const int s  = (int)(blockIdx.x >> 5);     // 0..15

    const char* kvbh = kv + (size_t)bh * 16 * TILE_BYTES;

    const half8 ones = {(_Float16)1.f, (_Float16)1.f, (_Float16)1.f, (_Float16)1.f,
                        (_Float16)1.f, (_Float16)1.f, (_Float16)1.f, (_Float16)1.f};
    const half2 c8  = {(_Float16)0.125f, (_Float16)0.125f};
    const half2 c1  = {(_Float16)1.f,    (_Float16)1.f};
    const half2 ch  = {(_Float16)0.5f,   (_Float16)0.5f};

    for (int p = 0; p < 2; ++p) {
        const int qi   = p ? (NQT - 1 - s) : s;
        const int q0   = qi * BM;
        const int jmax = qi;
        const float* qbase = qp + ((size_t)bh * Lc + q0) * Dc;

        // ---- issue Q global loads first (oldest vmem) ----
        floatx4 qv[8];
        const int r0 = tid >> 4, c4 = tid & 15;
        #pragma unroll
        for (int rep = 0; rep < 8; ++rep)
            qv[rep] = *(const floatx4*)(qbase + (r0 + rep * 16) * Dc + c4 * 4);

        // p==1: previous phase's epilogue LDS reads must finish before reuse
        __syncthreads();

        // ---- tile-0 DMA into buf0 ----
        {
            #pragma unroll
            for (int rep = 0; rep < 8; ++rep)
                dma16(kvbh + (rep * 256 + tid) * 16, smem + (rep * 256 + tid) * 16);
            if (tid < 192)
                dma16(kvbh + (2048 + tid) * 16, smem + (2048 + tid) * 16);
        }

        // ---- stage Q (fp32 -> bf16) into buf1's K area, extract per-strip B-frags ----
        {
            __bf16* Qs = (__bf16*)(smem + TILE_BYTES);
            #pragma unroll
            for (int rep = 0; rep < 8; ++rep) {
                bf16x4 b;
                b[0] = (__bf16)qv[rep][0]; b[1] = (__bf16)qv[rep][1];
                b[2] = (__bf16)qv[rep][2]; b[3] = (__bf16)qv[rep][3];
                *(bf16x4*)&Qs[(r0 + rep * 16) * LDQ + c4 * 4] = b;
            }
        }
        asm volatile("s_waitcnt lgkmcnt(0)" ::: "memory");
        __builtin_amdgcn_s_barrier();

        bf16x8 qa[4][2];   // [strip][kf]; B-frag: n=lm (qrow), k=kf*32+quad*8+j
        {
            const __bf16* Qs = (const __bf16*)(smem + TILE_BYTES);
            #pragma unroll
            for (int st = 0; st < 4; ++st)
                #pragma unroll
                for (int kf = 0; kf < 2; ++kf)
                    qa[st][kf] = *(const bf16x8*)&Qs[(64 * wq + 16 * st + lm) * LDQ + kf * 32 + quad * 8];
        }
        asm volatile("s_waitcnt lgkmcnt(0)" ::: "memory");
        __builtin_amdgcn_s_barrier();   // qa extracted before loop DMA overwrites buf1

        floatx4 oacc[4][4] = {};     // O^T partial (this wave's 64 keys): [strip][d-block]
        floatx4 zacc[4]    = {};     // z partial via ones-MFMA

        for (int j = 0; j <= jmax; ++j) {
            const int cur = j & 1;
            const __bf16*   Kc = (const __bf16*)(smem + cur * TILE_BYTES);
            const _Float16* Vc = (const _Float16*)(smem + cur * TILE_BYTES + KBYTES);

            // ---- issue next tile's DMA into the other buffer; counted vmcnt ----
            if (j < jmax) {
                const char* src = kvbh + (size_t)(j + 1) * TILE_BYTES;
                char* dst = smem + (cur ^ 1) * TILE_BYTES;
                #pragma unroll
                for (int rep = 0; rep < 8; ++rep)
                    dma16(src + (rep * 256 + tid) * 16, dst + (rep * 256 + tid) * 16);
                if (tid < 192)
                    dma16(src + (2048 + tid) * 16, dst + (2048 + tid) * 16);
                if (wv < 3) asm volatile("s_waitcnt vmcnt(9)" ::: "memory");
                else        asm volatile("s_waitcnt vmcnt(8)" ::: "memory");
            } else {
                asm volatile("s_waitcnt vmcnt(0)" ::: "memory");
            }
            __builtin_amdgcn_s_barrier();

            const bool nm = (j == jmax);                 // only the diagonal tile masks
            // skip fully-masked diagonal quadrant (rows 0..63 vs keys 64..127)
            const bool active = !(nm && wk && !wq);
            if (active) {
                // ---- two 32-key sub-phases of this wave's 64 keys ----
                #pragma unroll
                for (int hf = 0; hf < 2; ++hf) {
                    const int grp = 2 * wk + hf;         // 32-key group within the 128-tile

                    // S^T = K * Q^T for key rows [32*grp, 32*grp+32), all 4 q-strips
                    floatx4 sacc[4][2] = {};
                    #pragma unroll
                    for (int kb4 = 0; kb4 < 2; ++kb4) {
                        const int row0 = 16 * (4 * wk + 2 * hf + kb4);
                        #pragma unroll
                        for (int kf = 0; kf < 2; ++kf) {
                            bf16x8 ka = *(const bf16x8*)&Kc[(row0 + lm) * LDK + kf * 32 + quad * 8];
                            #pragma unroll
                            for (int st = 0; st < 4; ++st)
                                sacc[st][kb4] = __builtin_amdgcn_mfma_f32_16x16x32_bf16(ka, qa[st][kf], sacc[st][kb4], 0, 0, 0);
                        }
                    }

                    // packed-f16 Taylor + causal mask; wf = W B-frags (registers only)
                    half8 wf[4];
                    #pragma unroll
                    for (int st = 0; st < 4; ++st) {
                        const int thr = 64 * wq + 16 * st + lm;   // in-tile row (diag only)
                        half2 wh[2][2];
                        #pragma unroll
                        for (int kb4 = 0; kb4 < 2; ++kb4) {
                            half2 s01 = pack_f16(sacc[st][kb4][0], sacc[st][kb4][1]);
                            half2 s23 = pack_f16(sacc[st][kb4][2], sacc[st][kb4][3]);
                            half2 a01 = s01 * c8 + c1;            // fuses to v_pk_fma_f16
                            half2 a23 = s23 * c8 + c1;
                            half2 w01 = a01 * (a01 * ch) + ch;    // 0.5*a^2 + 0.5
                            half2 w23 = a23 * (a23 * ch) + ch;
                            if (nm) {
                                const int i0 = 16 * (4 * wk + 2 * hf + kb4) + 4 * quad;
                                w01[0] = (i0 + 0 <= thr) ? w01[0] : (_Float16)0.f;
                                w01[1] = (i0 + 1 <= thr) ? w01[1] : (_Float16)0.f;
                                w23[0] = (i0 + 2 <= thr) ? w23[0] : (_Float16)0.f;
                                w23[1] = (i0 + 3 <= thr) ? w23[1] : (_Float16)0.f;
                            }
                            wh[kb4][0] = w01;
                            wh[kb4][1] = w23;
                        }
                        half4 lo = __builtin_shufflevector(wh[0][0], wh[0][1], 0, 1, 2, 3);
                        half4 hi = __builtin_shufflevector(wh[1][0], wh[1][1], 0, 1, 2, 3);
                        wf[st] = __builtin_shufflevector(lo, hi, 0, 1, 2, 3, 4, 5, 6, 7);
                    }

                    // O^T += V^T * W^T (K=32 f16); va reused across 4 strips
                    #pragma unroll
                    for (int db = 0; db < 4; ++db) {
                        half8 va = *(const half8*)&Vc[(16 * db + lm) * LDV + 32 * grp + 8 * quad];
                        #pragma unroll
                        for (int st = 0; st < 4; ++st)
                            oacc[st][db] = __builtin_amdgcn_mfma_f32_16x16x32_f16(va, wf[st], oacc[st][db], 0, 0, 0);
                    }
                    #pragma unroll
                    for (int st = 0; st < 4; ++st)
                        zacc[st] = __builtin_amdgcn_mfma_f32_16x16x32_f16(ones, wf[st], zacc[st], 0, 0, 0);
                }
            }

            asm volatile("s_waitcnt lgkmcnt(0)" ::: "memory");
            __builtin_amdgcn_s_barrier();   // readers done before next iter's DMA
        }

        // ---- epilogue: cross-wave (wk) reduction through LDS, normalize, store ----
        float* Ored = (float*)smem;                     // [128][68] f32 = 34816 B (buf0)
        float* zred = (float*)(smem + 34816);           // [128]     f32 =   512 B
        if (wk) {
            #pragma unroll
            for (int st = 0; st < 4; ++st) {
                const int r = wq * 64 + 16 * st + lm;
                #pragma unroll
                for (int db = 0; db < 4; ++db)
                    *(floatx4*)&Ored[(size_t)r * 68 + 16 * db + 4 * quad] = oacc[st][db];
                zred[r] = zacc[st][0];
            }
        }
        __syncthreads();
        if (!wk) {
            #pragma unroll
            for (int st = 0; st < 4; ++st) {
                const int r = wq * 64 + 16 * st + lm;
                const float inv = 1.0f / (zacc[st][0] + zred[r] + 1e-6f);
                const int qrow = q0 + r;
                float* orow = op + ((size_t)bh * Lc + qrow) * Dc;
                #pragma unroll
                for (int db = 0; db < 4; ++db) {
                    floatx4 part = *(const floatx4*)&Ored[(size_t)r * 68 + 16 * db + 4 * quad];
                    floatx4 t = (oacc[st][db] + part) * inv;
                    *(floatx4*)&orow[16 * db + 4 * quad] = t;
                }
            }
        }
        // next phase's top __syncthreads() fences these Ored reads before LDS reuse
    }
}

extern "C" void kernel_launch(void* const* d_in, const int* in_sizes, int n_in,
                              void* d_out, int out_size, void* d_ws, size_t ws_size,
                              hipStream_t stream) {
    const float* q = (const float*)d_in[0];
    const float* k = (const float*)d_in[1];
    const float* v = (const float*)d_in[2];
    float* o = (float*)d_out;

    char* kv = (char*)d_ws;   // 32 bh x 16 tiles x 35840 B = 18.35 MB

    prep<<<dim3(2048), dim3(256), 0, stream>>>(k, v, kv);
    taylor_attn<<<dim3(NQT * BHn), dim3(256), 0, stream>>>(q, kv, o);
}

// Round 9
// 124.799 us; speedup vs baseline: 1.1111x; 1.1111x over previous
//
#include <hip/hip_runtime.h>
#include <hip/hip_bf16.h>

typedef __bf16    bf16x8  __attribute__((ext_vector_type(8)));
typedef __bf16    bf16x4  __attribute__((ext_vector_type(4)));
typedef _Float16  half8   __attribute__((ext_vector_type(8)));
typedef _Float16  half4   __attribute__((ext_vector_type(4)));
typedef _Float16  half2   __attribute__((ext_vector_type(2)));
typedef float     floatx4 __attribute__((ext_vector_type(4)));

constexpr int Bc  = 2;
constexpr int Hc  = 16;
constexpr int Lc  = 2048;
constexpr int Dc  = 64;
constexpr int BHn = Bc * Hc;     // 32
constexpr int BM  = 128;         // query rows per q-tile
constexpr int BN  = 128;         // keys per kv tile
constexpr int NQT = Lc / BM;     // 16 query tiles
constexpr int LDK = 72;          // K padded stride (bf16 elems) -> row = 144 B
constexpr int LDV = 136;         // V^T padded stride (f16 elems) -> row = 272 B
constexpr int LDQ = 72;          // Q staging stride (bf16) in buf1's K area
constexpr int KBYTES = BN * LDK * 2;            // 18432
constexpr int VBYTES = Dc * LDV * 2;            // 17408
constexpr int TILE_BYTES = KBYTES + VBYTES;     // 35840 (= LDS image of one tile)

static __device__ __forceinline__ half2 pack_f16(float a, float b) {
    return __builtin_bit_cast(half2, __builtin_amdgcn_cvt_pkrtz(a, b));
}

static __device__ __forceinline__ void dma16(const void* g, void* l) {
    __builtin_amdgcn_global_load_lds(
        (const __attribute__((address_space(1))) void*)g,
        (__attribute__((address_space(3))) void*)l, 16, 0, 0);
}

// ---- pre-pass: write K/V tiles in the exact padded LDS image ----
// kv layout: [bh][tile=16][ K: 128 rows x 144 B | V^T: 64 rows x 272 B ] = 35840 B/tile
// V^T value at [d][pcol] = V[key(pcol)][d]; pcol permutation within each 32-key group:
// k5 -> 8*((k5>>2)&3) + 4*(k5>>4) + (k5&3)  (makes PV A-frags b128-contiguous)
__global__ void prep(const float* __restrict__ kp, const float* __restrict__ vp,
                     char* __restrict__ kv) {
    const int bid = blockIdx.x, tid = threadIdx.x;
    if (bid < 1024) {
        // K part: 1024 blocks x 256 threads; 4 threads per K row (16 d each)
        const int R    = bid * 64 + (tid >> 2);   // global row: bh*2048 + key
        const int s    = tid & 3;
        const int bh   = R >> 11;
        const int key  = R & 2047;
        const int tile = key >> 7;
        const int krow = key & 127;
        const float* src = kp + (size_t)R * 64 + s * 16;
        char* dst = kv + (size_t)(bh * 16 + tile) * TILE_BYTES + krow * 144 + s * 32;
        #pragma unroll
        for (int h = 0; h < 2; ++h) {
            floatx4 a = *(const floatx4*)(src + h * 8);
            floatx4 b = *(const floatx4*)(src + h * 8 + 4);
            bf16x8 o;
            o[0] = (__bf16)a[0]; o[1] = (__bf16)a[1]; o[2] = (__bf16)a[2]; o[3] = (__bf16)a[3];
            o[4] = (__bf16)b[0]; o[5] = (__bf16)b[1]; o[6] = (__bf16)b[2]; o[7] = (__bf16)b[3];
            *(bf16x8*)(dst + h * 16) = o;
        }
    } else {
        // V part: 1024 blocks; block handles 64 keys (half a tile) x 64 d
        const int vb   = bid - 1024;
        const int bh   = vb >> 5, kt = vb & 31;
        const int key  = kt * 64 + (tid & 63);
        const int tile = kt >> 1;
        const int kwt  = (kt & 1) * 64 + (tid & 63);   // key within tile
        const int k5   = kwt & 31;
        const int pcol = (kwt & ~31) | (((k5 >> 2) & 3) * 8 + ((k5 >> 4) & 1) * 4 + (k5 & 3));
        const int d0   = (tid >> 6) * 16;
        const float* src = vp + ((size_t)bh * Lc + key) * Dc;
        _Float16* dst = (_Float16*)(kv + (size_t)(bh * 16 + tile) * TILE_BYTES + KBYTES);
        #pragma unroll
        for (int i = 0; i < 16; ++i) {
            const int d = d0 + i;
            dst[(size_t)d * LDV + pcol] = (_Float16)src[d];
        }
    }
}

// ---- main kernel: R2 structure + XCD-resident kv scheduling ----
// blockIdx decode (XCD = blockIdx%8 on MI355X): blockIdx = w*8 + (bh%8),
// w bits: [2:0]=qslot, [4:3]=bh>>3, [5]=snd. So each XCD serves only 4 bh
// (2.3 MB kv < 4 MB L2 -> all re-staging L2-hits), and co-CU pair (w, w+32)
// is same-bh complementary-qi (qslot vs 15-qslot): 17 iterations per CU.
__global__ __launch_bounds__(256, 2)
void taylor_attn(const float* __restrict__ qp, const char* __restrict__ kv,
                 float* __restrict__ op)
{
    __shared__ __align__(16) char smem[2 * TILE_BYTES];   // 71680 B: buf0 | buf1

    const int tid  = threadIdx.x;
    const int wv   = tid >> 6;
    const int lane = tid & 63;
    const int lm   = lane & 15;
    const int quad = lane >> 4;
    const int wq   = wv >> 1;   // q-half owner: rows [64*wq, 64*wq+64)
    const int wk   = wv & 1;    // key-half owner: keys [64*wk, 64*wk+64)

    const int r_    = (int)(blockIdx.x & 7);     // bh % 8  (XCD key)
    const int w_    = (int)(blockIdx.x >> 3);    // 0..63
    const int qslot = w_ & 7;
    const int bh    = r_ + 8 * ((w_ >> 3) & 3);
    const int snd   = (w_ >> 5) & 1;
    const int qi    = snd ? qslot : (NQT - 1 - qslot);
    const int q0    = qi * BM;
    const int jmax  = qi;

    const float* qbase = qp + ((size_t)bh * Lc + q0) * Dc;
    const char*  kvbh  = kv + (size_t)bh * 16 * TILE_BYTES;

    // ---- issue Q global loads first (oldest vmem), then tile-0 DMA into buf0 ----
    floatx4 qv[8];
    const int r0 = tid >> 4, c4 = tid & 15;
    #pragma unroll
    for (int rep = 0; rep < 8; ++rep)
        qv[rep] = *(const floatx4*)(qbase + (r0 + rep * 16) * Dc + c4 * 4);

    {
        const char* src = kvbh;          // tile 0
        #pragma unroll
        for (int rep = 0; rep < 8; ++rep)
            dma16(src + (rep * 256 + tid) * 16, smem + (rep * 256 + tid) * 16);
        if (tid < 192)
            dma16(src + (2048 + tid) * 16, smem + (2048 + tid) * 16);
    }

    // ---- stage Q (fp32 -> bf16) into buf1's K area, extract per-strip B-frags ----
    {
        __bf16* Qs = (__bf16*)(smem + TILE_BYTES);
        #pragma unroll
        for (int rep = 0; rep < 8; ++rep) {
            bf16x4 b;
            b[0] = (__bf16)qv[rep][0]; b[1] = (__bf16)qv[rep][1];
            b[2] = (__bf16)qv[rep][2]; b[3] = (__bf16)qv[rep][3];
            *(bf16x4*)&Qs[(r0 + rep * 16) * LDQ + c4 * 4] = b;
        }
    }
    asm volatile("s_waitcnt lgkmcnt(0)" ::: "memory");
    __builtin_amdgcn_s_barrier();

    bf16x8 qa[4][2];   // [strip][kf]; B-frag: n=lm (qrow), k=kf*32+quad*8+j
    {
        const __bf16* Qs = (const __bf16*)(smem + TILE_BYTES);
        #pragma unroll
        for (int st = 0; st < 4; ++st)
            #pragma unroll
            for (int kf = 0; kf < 2; ++kf)
                qa[st][kf] = *(const bf16x8*)&Qs[(64 * wq + 16 * st + lm) * LDQ + kf * 32 + quad * 8];
    }
    asm volatile("s_waitcnt lgkmcnt(0)" ::: "memory");
    __builtin_amdgcn_s_barrier();   // all qa extracted before loop DMA overwrites buf1

    floatx4 oacc[4][4] = {};     // O^T partial (this wave's 64 keys): [strip][d-block]
    floatx4 zacc[4]    = {};     // z partial via ones-MFMA

    const half8 ones = {(_Float16)1.f, (_Float16)1.f, (_Float16)1.f, (_Float16)1.f,
                        (_Float16)1.f, (_Float16)1.f, (_Float16)1.f, (_Float16)1.f};
    const half2 c8  = {(_Float16)0.125f, (_Float16)0.125f};
    const half2 c1  = {(_Float16)1.f,    (_Float16)1.f};
    const half2 ch  = {(_Float16)0.5f,   (_Float16)0.5f};

    for (int j = 0; j <= jmax; ++j) {
        const int cur = j & 1;
        const __bf16*   Kc = (const __bf16*)(smem + cur * TILE_BYTES);
        const _Float16* Vc = (const _Float16*)(smem + cur * TILE_BYTES + KBYTES);

        // ---- issue next tile's DMA into the other buffer; counted vmcnt (never 0) ----
        if (j < jmax) {
            const char* src = kvbh + (size_t)(j + 1) * TILE_BYTES;
            char* dst = smem + (cur ^ 1) * TILE_BYTES;
            #pragma unroll
            for (int rep = 0; rep < 8; ++rep)
                dma16(src + (rep * 256 + tid) * 16, dst + (rep * 256 + tid) * 16);
            if (tid < 192)
                dma16(src + (2048 + tid) * 16, dst + (2048 + tid) * 16);
            if (wv < 3) asm volatile("s_waitcnt vmcnt(9)" ::: "memory");
            else        asm volatile("s_waitcnt vmcnt(8)" ::: "memory");
        } else {
            asm volatile("s_waitcnt vmcnt(0)" ::: "memory");
        }
        __builtin_amdgcn_s_barrier();

        const bool nm = (j == jmax);                 // only the diagonal tile masks
        // skip fully-masked diagonal quadrant (rows 0..63 vs keys 64..127)
        const bool active = !(nm && wk && !wq);
        if (active) {
            // ---- two 32-key sub-phases of this wave's 64 keys ----
            #pragma unroll
            for (int hf = 0; hf < 2; ++hf) {
                const int grp = 2 * wk + hf;             // 32-key group within the 128-tile

                // S^T = K * Q^T for key rows [32*grp, 32*grp+32), all 4 q-strips
                floatx4 sacc[4][2] = {};
                #pragma unroll
                for (int kb4 = 0; kb4 < 2; ++kb4) {
                    const int row0 = 16 * (4 * wk + 2 * hf + kb4);
                    #pragma unroll
                    for (int kf = 0; kf < 2; ++kf) {
                        bf16x8 ka = *(const bf16x8*)&Kc[(row0 + lm) * LDK + kf * 32 + quad * 8];
                        #pragma unroll
                        for (int st = 0; st < 4; ++st)
                            sacc[st][kb4] = __builtin_amdgcn_mfma_f32_16x16x32_bf16(ka, qa[st][kf], sacc[st][kb4], 0, 0, 0);
                    }
                }

                // packed-f16 Taylor + causal mask; wf = W B-frags (registers only)
                half8 wf[4];
                #pragma unroll
                for (int st = 0; st < 4; ++st) {
                    const int thr = 64 * wq + 16 * st + lm;   // in-tile row (diag only)
                    half2 wh[2][2];
                    #pragma unroll
                    for (int kb4 = 0; kb4 < 2; ++kb4) {
                        half2 s01 = pack_f16(sacc[st][kb4][0], sacc[st][kb4][1]);
                        half2 s23 = pack_f16(sacc[st][kb4][2], sacc[st][kb4][3]);
                        half2 a01 = s01 * c8 + c1;            // fuses to v_pk_fma_f16
                        half2 a23 = s23 * c8 + c1;
                        half2 w01 = a01 * (a01 * ch) + ch;    // 0.5*a^2 + 0.5 = 1 + x + 0.5x^2
                        half2 w23 = a23 * (a23 * ch) + ch;
                        if (nm) {
                            const int i0 = 16 * (4 * wk + 2 * hf + kb4) + 4 * quad;
                            w01[0] = (i0 + 0 <= thr) ? w01[0] : (_Float16)0.f;
                            w01[1] = (i0 + 1 <= thr) ? w01[1] : (_Float16)0.f;
                            w23[0] = (i0 + 2 <= thr) ? w23[0] : (_Float16)0.f;
                            w23[1] = (i0 + 3 <= thr) ? w23[1] : (_Float16)0.f;
                        }
                        wh[kb4][0] = w01;
                        wh[kb4][1] = w23;
                    }
                    half4 lo = __builtin_shufflevector(wh[0][0], wh[0][1], 0, 1, 2, 3);
                    half4 hi = __builtin_shufflevector(wh[1][0], wh[1][1], 0, 1, 2, 3);
                    wf[st] = __builtin_shufflevector(lo, hi, 0, 1, 2, 3, 4, 5, 6, 7);
                }

                // O^T += V^T * W^T (K=32 f16) for this 32-key group; va reused across 4 strips
                #pragma unroll
                for (int db = 0; db < 4; ++db) {
                    half8 va = *(const half8*)&Vc[(16 * db + lm) * LDV + 32 * grp + 8 * quad];
                    #pragma unroll
                    for (int st = 0; st < 4; ++st)
                        oacc[st][db] = __builtin_amdgcn_mfma_f32_16x16x32_f16(va, wf[st], oacc[st][db], 0, 0, 0);
                }
                #pragma unroll
                for (int st = 0; st < 4; ++st)
                    zacc[st] = __builtin_amdgcn_mfma_f32_16x16x32_f16(ones, wf[st], zacc[st], 0, 0, 0);
            }
        }

        asm volatile("s_waitcnt lgkmcnt(0)" ::: "memory");
        __builtin_amdgcn_s_barrier();   // readers done before next iter's DMA overwrites
    }

    // ---- epilogue: cross-wave (wk) reduction through LDS, normalize, store ----
    float* Ored = (float*)smem;                     // [128][68] f32 = 34816 B (buf0 area)
    float* zred = (float*)(smem + 34816);           // [128]     f32 =   512 B
    if (wk) {
        #pragma unroll
        for (int st = 0; st < 4; ++st) {
            const int r = wq * 64 + 16 * st + lm;
            #pragma unroll
            for (int db = 0; db < 4; ++db)
                *(floatx4*)&Ored[(size_t)r * 68 + 16 * db + 4 * quad] = oacc[st][db];
            zred[r] = zacc[st][0];
        }
    }
    __syncthreads();
    if (!wk) {
        #pragma unroll
        for (int st = 0; st < 4; ++st) {
            const int r = wq * 64 + 16 * st + lm;
            const float inv = 1.0f / (zacc[st][0] + zred[r] + 1e-6f);
            const int qrow = q0 + r;
            float* orow = op + ((size_t)bh * Lc + qrow) * Dc;
            #pragma unroll
            for (int db = 0; db < 4; ++db) {
                floatx4 part = *(const floatx4*)&Ored[(size_t)r * 68 + 16 * db + 4 * quad];
                floatx4 t = (oacc[st][db] + part) * inv;
                *(floatx4*)&orow[16 * db + 4 * quad] = t;
            }
        }
    }
}

extern "C" void kernel_launch(void* const* d_in, const int* in_sizes, int n_in,
                              void* d_out, int out_size, void* d_ws, size_t ws_size,
                              hipStream_t stream) {
    const float* q = (const float*)d_in[0];
    const float* k = (const float*)d_in[1];
    const float* v = (const float*)d_in[2];
    float* o = (float*)d_out;

    char* kv = (char*)d_ws;   // 32 bh x 16 tiles x 35840 B = 18.35 MB

    prep<<<dim3(2048), dim3(256), 0, stream>>>(k, v, kv);
    taylor_attn<<<dim3(NQT * BHn), dim3(256), 0, stream>>>(q, kv, o);
}